// Round 11
// baseline (144.399 us; speedup 1.0000x reference)
//
#include <hip/hip_runtime.h>
#include <hip/hip_bf16.h>

// GQA causal attention fwd: B=1, H=16, HKV=4, S=2048, D=128, fp32 in/out.
// Round 11: occupancy attack. 512-thread blocks (8 waves = 2 qh x 4 kq),
// KVBLK=128, single-buffered K/Vt LDS (64KB) staged serially per tile via
// global_load_lds; 16 waves/CU = 4 waves/SIMD (2x r10). 32x32x16 MFMA,
// swapped QK^T + swapped PV, in-register P (cvt_pk+permlane32_swap), T13.
// 4-way kq merge epilogue in LDS. Counted-vmcnt reverted (r10: null).

#define NH    16
#define NHKV  4
#define SEQ   2048
#define DIM   128
#define QBLK  64
#define KVBLK 128
#define NT128 (SEQ / KVBLK)   // 16 kv tiles of 128

typedef __attribute__((ext_vector_type(8)))  short bf16x8_t;
typedef __attribute__((ext_vector_type(16))) float f32x16_t;

__device__ inline ushort f2bf(float f) {
    uint x = __float_as_uint(f);
    uint r = (x + 0x7fffu + ((x >> 16) & 1u)) >> 16;
    return (ushort)r;
}

__device__ inline uint cvtpk_bf16(float lo, float hi) {
    uint r;
    asm("v_cvt_pk_bf16_f32 %0, %1, %2" : "=v"(r) : "v"(lo), "v"(hi));
    return r;
}

#define GLOAD_LDS16(gsrc, ldst) \
    __builtin_amdgcn_global_load_lds( \
        (const __attribute__((address_space(1))) void*)(gsrc), \
        (__attribute__((address_space(3))) void*)(ldst), 16, 0, 0)

// ---- prep: K -> bf16 swizzled [kvh][tile128][row*256 + d*2 ^ ((row&7)<<4)]
//            V -> bf16 transposed swizzled [kvh][tile128][d*256 + kv*2 ^ ((d&7)<<4)]
// tile = 128 kv x 128 d = 32KB (1<<15)
extern "C" __global__ __launch_bounds__(256)
void prep_kv(const float* __restrict__ K, const float* __restrict__ V,
             ushort* __restrict__ Kpre, ushort* __restrict__ Vpre)
{
    int gid = blockIdx.x * 256 + threadIdx.x;
    if (blockIdx.x < 1024) {
        int kvh = gid >> 16; int rem = gid & 65535;
        int s = rem >> 5; int dq = (rem & 31) << 2;
        float4 f = *(const float4*)(K + ((size_t)(kvh * SEQ + s)) * DIM + dq);
        uint lo = (uint)f2bf(f.x) | ((uint)f2bf(f.y) << 16);
        uint hi = (uint)f2bf(f.z) | ((uint)f2bf(f.w) << 16);
        int tile = s >> 7, row = s & 127;
        uint byte = ((uint)(row * 256 + dq * 2)) ^ ((uint)(row & 7) << 4);
        *(uint2*)((char*)Kpre + (((size_t)(kvh * NT128 + tile)) << 15) + byte) =
            make_uint2(lo, hi);
    } else {
        int g2 = gid - 1024 * 256;
        int kvh = g2 >> 16; int rem = g2 & 65535;
        int d = rem & 127; int t2 = rem >> 7;          // 0..511
        int tile = t2 >> 5; int kvq = (t2 & 31) << 2;  // kv quad 0..124
        const float* b = V + ((size_t)(kvh * SEQ + tile * KVBLK + kvq)) * DIM + d;
        uint lo = (uint)f2bf(b[0])       | ((uint)f2bf(b[DIM]) << 16);
        uint hi = (uint)f2bf(b[2 * DIM]) | ((uint)f2bf(b[3 * DIM]) << 16);
        uint byte = ((uint)(d * 256 + kvq * 2)) ^ ((uint)(d & 7) << 4);
        *(uint2*)((char*)Vpre + (((size_t)(kvh * NT128 + tile)) << 15) + byte) =
            make_uint2(lo, hi);
    }
}

extern "C" __global__ __launch_bounds__(512, 4)
void attn_fwd(const float* __restrict__ Q, const ushort* __restrict__ Kpre,
              const ushort* __restrict__ Vpre, float* __restrict__ O)
{
    // pair heavy with light qt so per-CU load is uniform
    const int bid = blockIdx.x;
    const int h   = bid & 15;
    const int p   = bid >> 4;                 // 0..31
    const int qt  = (p < 16) ? p : 47 - p;    // QBLK=64 q-tile index
    const int kvh = h >> 2;                   // gqa_group_size = 4
    const int q0  = qt * QBLK;
    const int tid  = threadIdx.x;
    const int w    = tid >> 6;    // 0..7
    const int qh   = w >> 2;      // q-half (32 rows)
    const int kq   = w & 3;       // kv-quarter (32 of 128)
    const int lane = tid & 63;
    const int q31  = lane & 31;
    const int hi   = lane >> 5;

    // [K tile 32KB][Vt tile 32KB] single-buffered; merge epilogue reuses it
    __shared__ char smem[65536];
    char* smb = &smem[0];

    const float qscale = 0.08838834764831845f * 1.4426950408889634f; // 1/sqrt(D)*log2e

    // ---- Q fragments: B-frag of swapped QK^T (col = q = lane&31, k = hi*8+i)
    bf16x8_t qf[8];
    const int qrow = q0 + qh * 32 + q31;
    {
        const float* qp = Q + ((size_t)h * SEQ + qrow) * DIM + hi * 8;
#pragma unroll
        for (int ks = 0; ks < 8; ++ks) {
            float4 f0 = *(const float4*)(qp + ks * 16);
            float4 f1 = *(const float4*)(qp + ks * 16 + 4);
            bf16x8_t a;
            a[0] = (short)f2bf(f0.x * qscale); a[1] = (short)f2bf(f0.y * qscale);
            a[2] = (short)f2bf(f0.z * qscale); a[3] = (short)f2bf(f0.w * qscale);
            a[4] = (short)f2bf(f1.x * qscale); a[5] = (short)f2bf(f1.y * qscale);
            a[6] = (short)f2bf(f1.z * qscale); a[7] = (short)f2bf(f1.w * qscale);
            qf[ks] = a;
        }
    }

    // O^T accumulator: 4 d-tiles (d = m*32 + crow), col = q = lane&31
    f32x16_t oacc[4];
#pragma unroll
    for (int m = 0; m < 4; ++m)
#pragma unroll
        for (int i = 0; i < 16; ++i) oacc[m][i] = 0.f;
    float m_r = -1e30f, l_r = 0.f;   // per-lane softmax state for q = lane&31

    const int nt = (qt >> 1) + 1;    // kv tiles of 128 covering [0, q0+64)
    const size_t kvbase = (size_t)kvh * NT128;

    const int  krow = kq * 32 + q31;             // A-frag row of K (kv in tile)
    const uint kswz = ((uint)(krow & 7)) << 4;

    for (int t = 0; t < nt; ++t) {
        __syncthreads();   // prior tile's LDS reads complete
        {   // stage tile t: K 32KB + Vt 32KB, 8x16B per thread
            const char* kg = (const char*)Kpre + ((kvbase + t) << 15) + tid * 16;
            const char* vg = (const char*)Vpre + ((kvbase + t) << 15) + tid * 16;
            char* kl = smb + tid * 16;
            char* vl = smb + 32768 + tid * 16;
#pragma unroll
            for (int c = 0; c < 4; ++c) {
                GLOAD_LDS16(kg + c * 8192, kl + c * 8192);
                GLOAD_LDS16(vg + c * 8192, vl + c * 8192);
            }
        }
        __syncthreads();   // drains vmcnt + visibility

        // causal: off>0 full, off==0 diagonal, off<0 fully masked (32-aligned)
        int off = 32;
        if (t == nt - 1) off = q0 + qh * 32 - (t * KVBLK + kq * 32);
        if (off >= 0) {
            // ---- swapped QK^T: S^T[kv][q], one 32x32 tile per wave ----
            f32x16_t sacc;
#pragma unroll
            for (int i = 0; i < 16; ++i) sacc[i] = 0.f;
            __builtin_amdgcn_s_setprio(1);
#pragma unroll
            for (int ks = 0; ks < 8; ++ks) {
                uint byte = ((uint)(krow * 256 + ks * 32 + hi * 16)) ^ kswz;
                bf16x8_t kf = *(bf16x8_t*)(smb + byte);
                sacc = __builtin_amdgcn_mfma_f32_32x32x16_bf16(kf, qf[ks], sacc, 0, 0, 0);
            }
            __builtin_amdgcn_s_setprio(0);

            if (off == 0) {   // diagonal sub-tile mask
#pragma unroll
                for (int reg = 0; reg < 16; ++reg) {
                    int crow = (reg & 3) + 8 * (reg >> 2) + 4 * hi;   // kv-local
                    if (crow > q31) sacc[reg] = -1e30f;
                }
            }

            // ---- per-lane row max ----
            float pmax = sacc[0];
#pragma unroll
            for (int i = 1; i < 16; ++i) pmax = fmaxf(pmax, sacc[i]);
            pmax = fmaxf(pmax, __shfl_xor(pmax, 32, 64));

            // ---- T13 defer-rescale (exp2 domain, THR = 8) ----
            if (!__all(pmax - m_r <= 8.f)) {
                float mnew = fmaxf(m_r, pmax);
                float alpha = __builtin_exp2f(m_r - mnew);
                m_r = mnew;
                l_r *= alpha;
#pragma unroll
                for (int m = 0; m < 4; ++m)
#pragma unroll
                    for (int i = 0; i < 16; ++i) oacc[m][i] *= alpha;
            }

            // ---- P = exp2(S - m) ----
            float pv[16];
            float psum = 0.f;
#pragma unroll
            for (int i = 0; i < 16; ++i) {
                pv[i] = __builtin_exp2f(sacc[i] - m_r);
                psum += pv[i];
            }
            psum += __shfl_xor(psum, 32, 64);
            l_r += psum;

            // ---- in-register P -> PV B-frags via cvt_pk + permlane32_swap ----
            bf16x8_t pa[2];
#pragma unroll
            for (int hf = 0; hf < 2; ++hf) {
                uint a0 = cvtpk_bf16(pv[hf * 8 + 0], pv[hf * 8 + 1]);
                uint a1 = cvtpk_bf16(pv[hf * 8 + 2], pv[hf * 8 + 3]);
                uint b0 = cvtpk_bf16(pv[hf * 8 + 4], pv[hf * 8 + 5]);
                uint b1 = cvtpk_bf16(pv[hf * 8 + 6], pv[hf * 8 + 7]);
                asm volatile("v_permlane32_swap_b32 %0, %1" : "+v"(a0), "+v"(b0));
                asm volatile("v_permlane32_swap_b32 %0, %1" : "+v"(a1), "+v"(b1));
                uint4 tmp = make_uint4(a0, a1, b0, b1);
                pa[hf] = *(bf16x8_t*)&tmp;
            }

            // ---- swapped PV: O^T[d][q] += V^T[d][kv] P^T[kv][q] ----
            const char* vb = smb + 32768;
            __builtin_amdgcn_s_setprio(1);
#pragma unroll
            for (int m = 0; m < 4; ++m) {
                const int drow = m * 32 + q31;
                const uint vswz = ((uint)(drow & 7)) << 4;
#pragma unroll
                for (int ks2 = 0; ks2 < 2; ++ks2) {
                    uint byte = ((uint)(drow * 256 + kq * 64 + ks2 * 32 + hi * 16)) ^ vswz;
                    bf16x8_t vf = *(bf16x8_t*)(vb + byte);
                    oacc[m] = __builtin_amdgcn_mfma_f32_32x32x16_bf16(vf, pa[ks2], oacc[m], 0, 0, 0);
                }
            }
            __builtin_amdgcn_s_setprio(0);
        }
    }

    // ================= 4-way kq merge epilogue =================
    __syncthreads();
    // phase 0: m/l exchange  [qh][kq][2][32] f32 (1KB)
    float* ml = (float*)smb;
    if (hi == 0) {
        ml[((qh * 4 + kq) * 2 + 0) * 32 + q31] = m_r;
        ml[((qh * 4 + kq) * 2 + 1) * 32 + q31] = l_r;
    }
    __syncthreads();
    float mN = -1e30f;
#pragma unroll
    for (int i = 0; i < 4; ++i)
        mN = fmaxf(mN, ml[((qh * 4 + i) * 2 + 0) * 32 + q31]);
    float L = 0.f;
#pragma unroll
    for (int i = 0; i < 4; ++i)
        L += __builtin_exp2f(ml[((qh * 4 + i) * 2 + 0) * 32 + q31] - mN)
             * ml[((qh * 4 + i) * 2 + 1) * 32 + q31];
    float scale = __builtin_exp2f(m_r - mN) / L;
#pragma unroll
    for (int m = 0; m < 4; ++m)
#pragma unroll
        for (int i = 0; i < 16; ++i) oacc[m][i] *= scale;
    __syncthreads();   // ml reads done before partial writes reuse smem

    // phase 1+: tree-add scaled partials over kq. regions: [qh][128d][32q] f32
    float* reg0 = (float*)smb;               // 32KB (2 qh x 16KB)
    float* reg1 = (float*)(smb + 32768);     // 32KB
    {
        // write helpers inlined to keep static indexing
        if (kq == 1 || kq == 3) {
            float* dst = (kq == 1) ? reg0 : reg1;
#pragma unroll
            for (int m = 0; m < 4; ++m)
#pragma unroll
                for (int g = 0; g < 16; ++g) {
                    int d = m * 32 + (g & 3) + 8 * (g >> 2) + 4 * hi;
                    dst[(qh * 128 + d) * 32 + q31] = oacc[m][g];
                }
        }
        __syncthreads();
        if (kq == 0 || kq == 2) {
            const float* src = (kq == 0) ? reg0 : reg1;
#pragma unroll
            for (int m = 0; m < 4; ++m)
#pragma unroll
                for (int g = 0; g < 16; ++g) {
                    int d = m * 32 + (g & 3) + 8 * (g >> 2) + 4 * hi;
                    oacc[m][g] += src[(qh * 128 + d) * 32 + q31];
                }
        }
        __syncthreads();
        if (kq == 2) {
#pragma unroll
            for (int m = 0; m < 4; ++m)
#pragma unroll
                for (int g = 0; g < 16; ++g) {
                    int d = m * 32 + (g & 3) + 8 * (g >> 2) + 4 * hi;
                    reg0[(qh * 128 + d) * 32 + q31] = oacc[m][g];
                }
        }
        __syncthreads();
        if (kq == 0) {
#pragma unroll
            for (int m = 0; m < 4; ++m)
#pragma unroll
                for (int g = 0; g < 16; ++g) {
                    int d = m * 32 + (g & 3) + 8 * (g >> 2) + 4 * hi;
                    oacc[m][g] += reg0[(qh * 128 + d) * 32 + q31];
                }
            float* op = O + ((size_t)h * SEQ + qrow) * DIM;
#pragma unroll
            for (int m = 0; m < 4; ++m)
#pragma unroll
                for (int rq = 0; rq < 4; ++rq) {
                    int d0 = m * 32 + 8 * rq + 4 * hi;
                    float4 v;
                    v.x = oacc[m][rq * 4 + 0];
                    v.y = oacc[m][rq * 4 + 1];
                    v.z = oacc[m][rq * 4 + 2];
                    v.w = oacc[m][rq * 4 + 3];
                    *(float4*)(op + d0) = v;
                }
        }
    }
}

extern "C" void kernel_launch(void* const* d_in, const int* in_sizes, int n_in,
                              void* d_out, int out_size, void* d_ws, size_t ws_size,
                              hipStream_t stream) {
    const float* Q = (const float*)d_in[0];
    const float* K = (const float*)d_in[1];
    const float* V = (const float*)d_in[2];
    float* O = (float*)d_out;
    ushort* Kpre = (ushort*)d_ws;                          // 2 MB
    ushort* Vpre = (ushort*)((char*)d_ws + (2u << 20));    // 2 MB
    prep_kv<<<2048, 256, 0, stream>>>(K, V, Kpre, Vpre);
    attn_fwd<<<dim3(512), 512, 0, stream>>>(Q, Kpre, Vpre, O);
}